// Round 11
// baseline (372.640 us; speedup 1.0000x reference)
//
#include <hip/hip_runtime.h>

#define HID 256
#define NCLS 64
#define N_NODE 65536
#define N_TAB0 40000
#define N_TAB1 30000
#define S0 8
#define S1 4
#define TILES 2                       // node-tiles (16 rows) per wave-task
#define TOTROWS (N_TAB0 + N_TAB1 + N_NODE)
#define NBLK 256                      // persistent: one block per CU
#define BWAVES 8                      // 512-thread blocks
#define NTASK ((TOTROWS + TILES * 16 - 1) / (TILES * 16))   // 4236 32-row tasks

typedef __attribute__((ext_vector_type(8))) _Float16 f16x8;
typedef __attribute__((ext_vector_type(4))) float f32x4;

__device__ __forceinline__ unsigned short f32_to_h(float x) {
  _Float16 h = (_Float16)x;                      // v_cvt_f16_f32, RTNE
  return __builtin_bit_cast(unsigned short, h);
}
__device__ __forceinline__ unsigned pack2h(float lo, float hi) {
  return (unsigned)f32_to_h(lo) | ((unsigned)f32_to_h(hi) << 16);
}

// Pre-convert W1^T and W2^T into MFMA A-fragment order, SINGLE fp16.
// w1 frag f = nt*8+kt occupies halves [f*512,(f+1)*512): ((nt*8+kt)*64+lane)*8+j
//   -> W1[kt*32 + (lane>>4)*8 + j][nt*16 + (lane&15)]
// w2 frag f = ct*8+kt likewise -> W2[kt*32 + (lane>>4)*8 + j][ct*16 + (lane&15)]
__global__ void prep_kernel(const float* __restrict__ W1, const float* __restrict__ W2,
                            unsigned short* __restrict__ w1f, unsigned short* __restrict__ w2f) {
  int t = blockIdx.x * blockDim.x + threadIdx.x;
  if (t < HID * HID) {
    int j = t & 7, l = (t >> 3) & 63, kt = (t >> 9) & 7, nt = t >> 12;
    w1f[t] = f32_to_h(W1[(kt * 32 + (l >> 4) * 8 + j) * HID + nt * 16 + (l & 15)]);
  } else {
    int t2 = t - HID * HID;
    if (t2 < HID * NCLS) {
      int j = t2 & 7, l = (t2 >> 3) & 63, kt = (t2 >> 9) & 7, ct = t2 >> 12;
      w2f[t2] = f32_to_h(W2[(kt * 32 + (l >> 4) * 8 + j) * NCLS + ct * 16 + (l & 15)]);
    }
  }
}

// PERSISTENT-BLOCK design (R11). 256 blocks x 512 threads = one block per CU,
// 8 waves. The ENTIRE fp16 W1 (128 KB, frag-ordered) is staged into LDS ONCE
// (16 global_load_lds per wave), ONE __syncthreads, then each of the 2048 waves
// independently grid-strides over 32-row tasks (4236 tasks, ~2.07/wave) with
// ZERO barriers: X-pack -> 16 LDS slices -> repack -> phase-2 -> softmax ->
// store, loop. Rationale (R0-R10 ledger): every prior structure paid per-block
// W1 re-staging (128 KB L2->LDS x 1059 blocks) + barrier pipeline drains for
// only 128 rows of output; all sync-microstructure levers are exhausted
// (vmcnt ring R4, chains R9, repack overlap R10 - all null). Real pipe work is
// ~25-35 us/CU; the rest was block ramp overhead.
// Differs from failed attempts: R1 read W1 from L2 per fragment (no reuse);
// R8's 1024-thr block capped VGPR at 128 and spilled (VGPR_Count 52). Here the
// 512-thr block caps VGPR at 256 >= ~180 live state.
// VGPR tripwires (R5/R8): reported VGPR <=100 for this kernel means the
// persistent X/lg state spilled; expect 130-220.
__launch_bounds__(512, 1)
__global__ void mlp_all_kernel(const float* __restrict__ tab0, const float* __restrict__ tab1,
                               const float* __restrict__ h0,
                               const unsigned short* __restrict__ w1f,
                               const float* __restrict__ b1,
                               const unsigned short* __restrict__ w2f,
                               const float* __restrict__ b2,
                               float* __restrict__ cls0, float* __restrict__ cls1,
                               float* __restrict__ out,
                               const float* __restrict__ alpha) {
  __shared__ __align__(16) char Wlds[131072];   // full fp16 W1, frag-ordered

  const int t = threadIdx.x;
  const int lane = t & 63;
  const int wv = t >> 6;                // 0..7
  const int nr = lane & 15;
  const int u = lane >> 4;
  const int lo16 = lane * 16;
  const int wgid = blockIdx.x * BWAVES + wv;   // 0..2047

  // ---- stage ALL of W1 once: 128 frags of 1 KB; wave wv loads frags wv*16..+15 ----
#pragma unroll
  for (int i = 0; i < 16; ++i) {
    const int q = wv * 16 + i;
    __builtin_amdgcn_global_load_lds(
        (const __attribute__((address_space(1))) void*)(w1f + (size_t)q * 512 + lane * 8),
        (__attribute__((address_space(3))) void*)(Wlds + q * 1024), 16, 0, 0);
  }

  const f16x8* W2F = (const f16x8*)w2f;

  // bpermute byte-addresses: dest dword m pulls from lane nr + 16*(2*(u&1) + (m>>1))
  int addr[4];
#pragma unroll
  for (int m = 0; m < 4; ++m) addr[m] = (nr + 16 * (2 * (u & 1) + (m >> 1))) * 4;
  const bool useOdd = (u >= 2);

  __syncthreads();   // W1 staged (drains vmcnt); NO barriers after this point

  for (int task = wgid; task < NTASK; task += NBLK * BWAVES) {
    const int base = task * (TILES * 16);

    // ---- X as B-fragments in registers, single fp16 ----
    f16x8 bx[TILES][8];
#pragma unroll
    for (int tl = 0; tl < TILES; ++tl) {
      const int row = base + tl * 16 + nr;
      const float* src;
      int lrow;
      if (row < N_TAB0) { src = tab0; lrow = row; }
      else if (row < N_TAB0 + N_TAB1) { src = tab1; lrow = row - N_TAB0; }
      else { src = h0; lrow = row - (N_TAB0 + N_TAB1); }
      const bool rok = (row < TOTROWS);
      const float* xrow = src + (size_t)lrow * HID;
#pragma unroll
      for (int kt = 0; kt < 8; ++kt) {
        float xv[8];
        if (rok) {
          float4 a = *(const float4*)&xrow[kt * 32 + u * 8];
          float4 b = *(const float4*)&xrow[kt * 32 + u * 8 + 4];
          xv[0] = a.x; xv[1] = a.y; xv[2] = a.z; xv[3] = a.w;
          xv[4] = b.x; xv[5] = b.y; xv[6] = b.z; xv[7] = b.w;
        } else {
#pragma unroll
          for (int j = 0; j < 8; ++j) xv[j] = 0.f;
        }
        f16x8 pk;
#pragma unroll
        for (int j = 0; j < 8; ++j) pk[j] = (_Float16)xv[j];
        bx[tl][kt] = pk;
      }
    }

    // ---- logits accumulators (bias-init) ----
    f32x4 lg[TILES][4];
#pragma unroll
    for (int ct = 0; ct < 4; ++ct) {
      float4 bv = *(const float4*)&b2[ct * 16 + u * 4];
#pragma unroll
      for (int tl = 0; tl < TILES; ++tl) {
        lg[tl][ct][0] = bv.x; lg[tl][ct][1] = bv.y;
        lg[tl][ct][2] = bv.z; lg[tl][ct][3] = bv.w;
      }
    }

    for (int kt2 = 0; kt2 < 8; ++kt2) {
      // preload this kt2's W2 fragments early: L1/L2 latency hides under slices
      f16x8 aw[4];
#pragma unroll
      for (int ct = 0; ct < 4; ++ct) aw[ct] = W2F[(ct * 8 + kt2) * 64 + lane];

      // phase-1: two slices (nt = 2*kt2, 2*kt2+1) from the static W1 LDS image
      unsigned E0[TILES], E1[TILES], O0[TILES], O1[TILES];
#pragma unroll
      for (int half = 0; half < 2; ++half) {
        const int nt = kt2 * 2 + half;
        const char* wb = Wlds + nt * 8192;
        f32x4 ae[TILES], ao[TILES];
        float4 bv = *(const float4*)&b1[nt * 16 + u * 4];
#pragma unroll
        for (int tl = 0; tl < TILES; ++tl) {
          ae[tl][0] = bv.x; ae[tl][1] = bv.y; ae[tl][2] = bv.z; ae[tl][3] = bv.w;
          ao[tl][0] = 0.f;  ao[tl][1] = 0.f;  ao[tl][2] = 0.f;  ao[tl][3] = 0.f;
        }
#pragma unroll
        for (int kt = 0; kt < 8; kt += 2) {
          f16x8 ah0 = *(const f16x8*)(wb + kt * 1024 + lo16);
          f16x8 ah1 = *(const f16x8*)(wb + (kt + 1) * 1024 + lo16);
#pragma unroll
          for (int tl = 0; tl < TILES; ++tl) {
            ae[tl] = __builtin_amdgcn_mfma_f32_16x16x32_f16(ah0, bx[tl][kt], ae[tl], 0, 0, 0);
            ao[tl] = __builtin_amdgcn_mfma_f32_16x16x32_f16(ah1, bx[tl][kt + 1], ao[tl], 0, 0, 0);
          }
        }
#pragma unroll
        for (int tl = 0; tl < TILES; ++tl) {
          unsigned p0 = pack2h(fmaxf(ae[tl][0] + ao[tl][0], 0.f), fmaxf(ae[tl][1] + ao[tl][1], 0.f));
          unsigned p1 = pack2h(fmaxf(ae[tl][2] + ao[tl][2], 0.f), fmaxf(ae[tl][3] + ao[tl][3], 0.f));
          if (half == 0) { E0[tl] = p0; E1[tl] = p1; }
          else           { O0[tl] = p0; O1[tl] = p1; }
        }
      }

      // repack to phase-2 B-frags: lane (u,nr) dword m = H dims (kt2*32 + u*8 + 2m, +1)
      f16x8 bh[TILES];
#pragma unroll
      for (int tl = 0; tl < TILES; ++tl) {
        union { unsigned d[4]; f16x8 v; } r;
#pragma unroll
        for (int m = 0; m < 4; ++m) {
          int e = __builtin_amdgcn_ds_bpermute(addr[m], (int)((m & 1) ? E1[tl] : E0[tl]));
          int o = __builtin_amdgcn_ds_bpermute(addr[m], (int)((m & 1) ? O1[tl] : O0[tl]));
          r.d[m] = (unsigned)(useOdd ? o : e);
        }
        bh[tl] = r.v;
      }

      // phase 2: accumulate logits for this 32-dim H block
#pragma unroll
      for (int ct = 0; ct < 4; ++ct) {
#pragma unroll
        for (int tl = 0; tl < TILES; ++tl) {
          lg[tl][ct] = __builtin_amdgcn_mfma_f32_16x16x32_f16(aw[ct], bh[tl], lg[tl][ct], 0, 0, 0);
        }
      }
    }

    // ---- softmax + segment-resolved write, per tile ----
#pragma unroll
    for (int tl = 0; tl < TILES; ++tl) {
      const int row = base + tl * 16 + nr;
      float m = lg[tl][0][0];
#pragma unroll
      for (int ct = 0; ct < 4; ++ct)
#pragma unroll
        for (int r = 0; r < 4; ++r) m = fmaxf(m, lg[tl][ct][r]);
      m = fmaxf(m, __shfl_xor(m, 16, 64));
      m = fmaxf(m, __shfl_xor(m, 32, 64));
      float p[4][4];
      float s = 0.f;
#pragma unroll
      for (int ct = 0; ct < 4; ++ct)
#pragma unroll
        for (int r = 0; r < 4; ++r) { p[ct][r] = __expf(lg[tl][ct][r] - m); s += p[ct][r]; }
      s += __shfl_xor(s, 16, 64);
      s += __shfl_xor(s, 32, 64);
      float inv = 1.f / s;

      float* dst;
      int lrow;
      if (row < N_TAB0) { dst = cls0; lrow = row; }
      else if (row < N_TAB0 + N_TAB1) { dst = cls1; lrow = row - N_TAB0; }
      else {
        dst = out; lrow = row - (N_TAB0 + N_TAB1);
        if (row < TOTROWS) inv *= 1.f / (1.f + __expf(-alpha[lrow]));  // a * p
      }

      if (row < TOTROWS) {
#pragma unroll
        for (int ct = 0; ct < 4; ++ct) {
          float4 o;
          o.x = p[ct][0] * inv; o.y = p[ct][1] * inv;
          o.z = p[ct][2] * inv; o.w = p[ct][3] * inv;
          *(float4*)&dst[(size_t)lrow * NCLS + ct * 16 + u * 4] = o;
        }
      }
    }
  }
}

// Gather-average 12 neighbor class rows and blend: out += (1-a)*0.5*(s0/8 + s1/4).
__launch_bounds__(256)
__global__ void blend_kernel(const float* __restrict__ cls0, const float* __restrict__ cls1,
                             const int* __restrict__ idx0, const int* __restrict__ idx1,
                             const float* __restrict__ alpha, float* __restrict__ out) {
  const int t = threadIdx.x;
  const int lane = t & 63;
  const int wv = t >> 6;
  const int g = lane >> 4;
  const int q = lane & 15;
  const int n = blockIdx.x * 16 + wv * 4 + g;

  int4 ia = *(const int4*)&idx0[n * S0];
  int4 ib = *(const int4*)&idx0[n * S0 + 4];
  int4 ic = *(const int4*)&idx1[n * S1];
  const int j0[S0] = {ia.x, ia.y, ia.z, ia.w, ib.x, ib.y, ib.z, ib.w};
  const int j1[S1] = {ic.x, ic.y, ic.z, ic.w};

  float4 s0 = make_float4(0.f, 0.f, 0.f, 0.f);
#pragma unroll
  for (int k = 0; k < S0; ++k) {
    float4 gv = *(const float4*)&cls0[(size_t)j0[k] * NCLS + q * 4];
    s0.x += gv.x; s0.y += gv.y; s0.z += gv.z; s0.w += gv.w;
  }
  float4 s1 = make_float4(0.f, 0.f, 0.f, 0.f);
#pragma unroll
  for (int k = 0; k < S1; ++k) {
    float4 gv = *(const float4*)&cls1[(size_t)j1[k] * NCLS + q * 4];
    s1.x += gv.x; s1.y += gv.y; s1.z += gv.z; s1.w += gv.w;
  }

  const float a = 1.f / (1.f + __expf(-alpha[n]));
  const float w = (1.f - a) * 0.5f;
  const float c0 = w * (1.f / S0);
  const float c1 = w * (1.f / S1);

  float* op = &out[(size_t)n * NCLS + q * 4];
  float4 o = *(const float4*)op;
  o.x += c0 * s0.x + c1 * s1.x;
  o.y += c0 * s0.y + c1 * s1.y;
  o.z += c0 * s0.z + c1 * s1.z;
  o.w += c0 * s0.w + c1 * s1.w;
  *(float4*)op = o;
}

extern "C" void kernel_launch(void* const* d_in, const int* in_sizes, int n_in,
                              void* d_out, int out_size, void* d_ws, size_t ws_size,
                              hipStream_t stream) {
  const float* h0    = (const float*)d_in[0];
  const float* tab0  = (const float*)d_in[1];
  const float* tab1  = (const float*)d_in[2];
  const int*   idx0  = (const int*)d_in[3];
  const int*   idx1  = (const int*)d_in[4];
  const float* W1    = (const float*)d_in[5];
  const float* b1    = (const float*)d_in[6];
  const float* W2    = (const float*)d_in[7];
  const float* b2    = (const float*)d_in[8];
  const float* alpha = (const float*)d_in[9];
  float* out = (float*)d_out;

  char* ws = (char*)d_ws;
  float* cls0 = (float*)ws;                                   // 10,240,000 B
  float* cls1 = (float*)(ws + 10240000);                      //  7,680,000 B
  unsigned short* w1f = (unsigned short*)(ws + 17920000);     //    131,072 B
  unsigned short* w2f = (unsigned short*)(ws + 18051072);     //     32,768 B

  prep_kernel<<<(HID * HID + HID * NCLS) / 256, 256, 0, stream>>>(W1, W2, w1f, w2f);

  mlp_all_kernel<<<NBLK, 512, 0, stream>>>(
      tab0, tab1, h0, w1f, b1, w2f, b2, cls0, cls1, out, alpha);

  blend_kernel<<<N_NODE / 16, 256, 0, stream>>>(cls0, cls1, idx0, idx1, alpha, out);
}

// Round 12
// 92.059 us; speedup vs baseline: 4.0478x; 4.0478x over previous
//
#include <hip/hip_runtime.h>

#define HID 256
#define NCLS 64
#define N_NODE 65536
#define N_TAB0 40000
#define N_TAB1 30000
#define S0 8
#define S1 4
#define TILES 1                       // 16 rows/wave: shrinks combined VGPR+AGPR under the 128
                                      // occupancy boundary (R7's TILES=2 was ~132 -> 3 waves/SIMD)
#define TOTROWS (N_TAB0 + N_TAB1 + N_NODE)
#define PBUF 16384                    // 16 KB pair-buffer (2 fp16 slices); x2 ping-pong = 32 KB

typedef __attribute__((ext_vector_type(8))) _Float16 f16x8;
typedef __attribute__((ext_vector_type(4))) float f32x4;

__device__ __forceinline__ unsigned short f32_to_h(float x) {
  _Float16 h = (_Float16)x;                      // v_cvt_f16_f32, RTNE
  return __builtin_bit_cast(unsigned short, h);
}
__device__ __forceinline__ unsigned pack2h(float lo, float hi) {
  return (unsigned)f32_to_h(lo) | ((unsigned)f32_to_h(hi) << 16);
}

// Pre-convert W1^T and W2^T into MFMA A-fragment order, SINGLE fp16.
// w1 frag f = nt*8+kt occupies halves [f*512,(f+1)*512): ((nt*8+kt)*64+lane)*8+j
//   -> W1[kt*32 + (lane>>4)*8 + j][nt*16 + (lane&15)]
// w2 frag f = ct*8+kt likewise -> W2[kt*32 + (lane>>4)*8 + j][ct*16 + (lane&15)]
__global__ void prep_kernel(const float* __restrict__ W1, const float* __restrict__ W2,
                            unsigned short* __restrict__ w1f, unsigned short* __restrict__ w2f) {
  int t = blockIdx.x * blockDim.x + threadIdx.x;
  if (t < HID * HID) {
    int j = t & 7, l = (t >> 3) & 63, kt = (t >> 9) & 7, nt = t >> 12;
    w1f[t] = f32_to_h(W1[(kt * 32 + (l >> 4) * 8 + j) * HID + nt * 16 + (l & 15)]);
  } else {
    int t2 = t - HID * HID;
    if (t2 < HID * NCLS) {
      int j = t2 & 7, l = (t2 >> 3) & 63, kt = (t2 >> 9) & 7, ct = t2 >> 12;
      w2f[t2] = f32_to_h(W2[(kt * 32 + (l >> 4) * 8 + j) * NCLS + ct * 16 + (l & 15)]);
    }
  }
}

// One kernel over concatenated rows [tab0 | tab1 | h0]. 4 waves/block, wave owns
// ONE 16-row tile (grid 2118, 8.3 blocks/CU). W1 staged TWO nt-slices per
// interval (16 KB fp16 pair) into a 2x16KB LDS ping-pong via global_load_lds;
// 8 barriers/block (R7's best schedule). W2 frags preloaded at interval top.
//
// R12 CHANGE: TILES=1 + __launch_bounds__(256,4). gfx950's unified VGPR/AGPR
// file means R7's "84 VGPR" was really ~132 combined (ae/ao + lg accumulators
// are AGPRs) -> 3 waves/SIMD, the hidden occupancy cap of R0-R10. TILES=1
// state is ~100 combined; the (256,4) bound pins allocation under 128 ->
// 4 waves/SIMD, 4 blocks/CU resident (LDS allows 5) = 2x latency hiding.
// Safe vs R5/R11 spills because the state actually fits the cap this time.
// Spill tripwires: VGPR_Count <=64 or WRITE_SIZE >> 34 MB -> theory dead.
__launch_bounds__(256, 4)
__global__ void mlp_all_kernel(const float* __restrict__ tab0, const float* __restrict__ tab1,
                               const float* __restrict__ h0,
                               const unsigned short* __restrict__ w1f,
                               const float* __restrict__ b1,
                               const unsigned short* __restrict__ w2f,
                               const float* __restrict__ b2,
                               float* __restrict__ cls0, float* __restrict__ cls1,
                               float* __restrict__ out,
                               const float* __restrict__ alpha) {
  __shared__ __align__(16) char Wlds[2 * PBUF];   // 32 KB

  const int t = threadIdx.x;
  const int lane = t & 63;
  const int wv = t >> 6;
  const int nr = lane & 15;
  const int u = lane >> 4;
  const int base = (blockIdx.x * 4 + wv) * (TILES * 16);
  const int lo16 = lane * 16;

  // ---- stage one PAIR of nt-slices (16 frags of 1 KB); wave wv does q=wv*4..+3 ----
  auto STAGE = [&](int pair, int bsel) {
    char* dst = Wlds + bsel * PBUF;
#pragma unroll
    for (int i = 0; i < 4; ++i) {
      const int q = wv * 4 + i;
      const unsigned short* src = w1f + (size_t)(pair * 16 + q) * 512;
      __builtin_amdgcn_global_load_lds(
          (const __attribute__((address_space(1))) void*)(src + lane * 8),
          (__attribute__((address_space(3))) void*)(dst + q * 1024), 16, 0, 0);
    }
  };

  // issue the first pair before the long X-pack prologue so L2 latency hides
  STAGE(0, 0);

  // ---- X as B-fragments in registers, single fp16 ----
  f16x8 bx[TILES][8];
#pragma unroll
  for (int tl = 0; tl < TILES; ++tl) {
    const int row = base + tl * 16 + nr;
    const float* src;
    int lrow;
    if (row < N_TAB0) { src = tab0; lrow = row; }
    else if (row < N_TAB0 + N_TAB1) { src = tab1; lrow = row - N_TAB0; }
    else { src = h0; lrow = row - (N_TAB0 + N_TAB1); }
    const bool rok = (row < TOTROWS);
    const float* xrow = src + (size_t)lrow * HID;
#pragma unroll
    for (int kt = 0; kt < 8; ++kt) {
      float xv[8];
      if (rok) {
        float4 a = *(const float4*)&xrow[kt * 32 + u * 8];
        float4 b = *(const float4*)&xrow[kt * 32 + u * 8 + 4];
        xv[0] = a.x; xv[1] = a.y; xv[2] = a.z; xv[3] = a.w;
        xv[4] = b.x; xv[5] = b.y; xv[6] = b.z; xv[7] = b.w;
      } else {
#pragma unroll
        for (int j = 0; j < 8; ++j) xv[j] = 0.f;
      }
      f16x8 pk;
#pragma unroll
      for (int j = 0; j < 8; ++j) pk[j] = (_Float16)xv[j];
      bx[tl][kt] = pk;
    }
  }

  // ---- logits accumulators (bias-init) ----
  f32x4 lg[TILES][4];
#pragma unroll
  for (int ct = 0; ct < 4; ++ct) {
    float4 bv = *(const float4*)&b2[ct * 16 + u * 4];
#pragma unroll
    for (int tl = 0; tl < TILES; ++tl) {
      lg[tl][ct][0] = bv.x; lg[tl][ct][1] = bv.y;
      lg[tl][ct][2] = bv.z; lg[tl][ct][3] = bv.w;
    }
  }

  const f16x8* W2F = (const f16x8*)w2f;

  // bpermute byte-addresses: dest dword m pulls from lane nr + 16*(2*(u&1) + (m>>1))
  int addr[4];
#pragma unroll
  for (int m = 0; m < 4; ++m) addr[m] = (nr + 16 * (2 * (u & 1) + (m >> 1))) * 4;
  const bool useOdd = (u >= 2);

  // phase-1 slice: read W1 frags from pair buffer, even/odd MFMA chains.
  // slice nt lives in buffer (nt>>1)&1 at sub-offset (nt&1)*8192.
  auto slice = [&](int nt, unsigned* P0, unsigned* P1) {
    const char* wb = Wlds + ((nt >> 1) & 1) * PBUF + (nt & 1) * 8192;
    f32x4 ae[TILES], ao[TILES];
    float4 bv = *(const float4*)&b1[nt * 16 + u * 4];
#pragma unroll
    for (int tl = 0; tl < TILES; ++tl) {
      ae[tl][0] = bv.x; ae[tl][1] = bv.y; ae[tl][2] = bv.z; ae[tl][3] = bv.w;
      ao[tl][0] = 0.f;  ao[tl][1] = 0.f;  ao[tl][2] = 0.f;  ao[tl][3] = 0.f;
    }
#pragma unroll
    for (int kt = 0; kt < 8; kt += 2) {
      f16x8 ah0 = *(const f16x8*)(wb + kt * 1024 + lo16);
      f16x8 ah1 = *(const f16x8*)(wb + (kt + 1) * 1024 + lo16);
#pragma unroll
      for (int tl = 0; tl < TILES; ++tl) {
        ae[tl] = __builtin_amdgcn_mfma_f32_16x16x32_f16(ah0, bx[tl][kt], ae[tl], 0, 0, 0);
        ao[tl] = __builtin_amdgcn_mfma_f32_16x16x32_f16(ah1, bx[tl][kt + 1], ao[tl], 0, 0, 0);
      }
    }
#pragma unroll
    for (int tl = 0; tl < TILES; ++tl) {
      P0[tl] = pack2h(fmaxf(ae[tl][0] + ao[tl][0], 0.f), fmaxf(ae[tl][1] + ao[tl][1], 0.f));
      P1[tl] = pack2h(fmaxf(ae[tl][2] + ao[tl][2], 0.f), fmaxf(ae[tl][3] + ao[tl][3], 0.f));
    }
  };

  __syncthreads();   // pair 0 staged

  for (int kt2 = 0; kt2 < 8; ++kt2) {
    // prefetch next pair into the other buffer (loads stay in flight the whole interval)
    if (kt2 + 1 < 8) STAGE(kt2 + 1, (kt2 + 1) & 1);

    // preload this interval's W2 fragments early: L2 latency hides under slices
    f16x8 aw[4];
#pragma unroll
    for (int ct = 0; ct < 4; ++ct) aw[ct] = W2F[(ct * 8 + kt2) * 64 + lane];

    unsigned E0[TILES], E1[TILES], O0[TILES], O1[TILES];
    slice(kt2 * 2, E0, E1);
    slice(kt2 * 2 + 1, O0, O1);

    // repack to phase-2 B-frags: lane (u,nr) dword m = H dims (kt2*32 + u*8 + 2m, +1)
    f16x8 bh[TILES];
#pragma unroll
    for (int tl = 0; tl < TILES; ++tl) {
      union { unsigned d[4]; f16x8 v; } r;
#pragma unroll
      for (int m = 0; m < 4; ++m) {
        int e = __builtin_amdgcn_ds_bpermute(addr[m], (int)((m & 1) ? E1[tl] : E0[tl]));
        int o = __builtin_amdgcn_ds_bpermute(addr[m], (int)((m & 1) ? O1[tl] : O0[tl]));
        r.d[m] = (unsigned)(useOdd ? o : e);
      }
      bh[tl] = r.v;
    }

    // phase 2: accumulate logits for this 32-dim H block
#pragma unroll
    for (int ct = 0; ct < 4; ++ct) {
#pragma unroll
      for (int tl = 0; tl < TILES; ++tl) {
        lg[tl][ct] = __builtin_amdgcn_mfma_f32_16x16x32_f16(aw[ct], bh[tl], lg[tl][ct], 0, 0, 0);
      }
    }

    // one barrier per interval: next pair staged (syncthreads drains own vmcnt,
    // barrier makes it global) + this buffer's reads done before overwrite.
    if (kt2 + 1 < 8) __syncthreads();
  }

  // ---- softmax + segment-resolved write, per tile ----
#pragma unroll
  for (int tl = 0; tl < TILES; ++tl) {
    const int row = base + tl * 16 + nr;
    float m = lg[tl][0][0];
#pragma unroll
    for (int ct = 0; ct < 4; ++ct)
#pragma unroll
      for (int r = 0; r < 4; ++r) m = fmaxf(m, lg[tl][ct][r]);
    m = fmaxf(m, __shfl_xor(m, 16, 64));
    m = fmaxf(m, __shfl_xor(m, 32, 64));
    float p[4][4];
    float s = 0.f;
#pragma unroll
    for (int ct = 0; ct < 4; ++ct)
#pragma unroll
      for (int r = 0; r < 4; ++r) { p[ct][r] = __expf(lg[tl][ct][r] - m); s += p[ct][r]; }
    s += __shfl_xor(s, 16, 64);
    s += __shfl_xor(s, 32, 64);
    float inv = 1.f / s;

    float* dst;
    int lrow;
    if (row < N_TAB0) { dst = cls0; lrow = row; }
    else if (row < N_TAB0 + N_TAB1) { dst = cls1; lrow = row - N_TAB0; }
    else {
      dst = out; lrow = row - (N_TAB0 + N_TAB1);
      if (row < TOTROWS) inv *= 1.f / (1.f + __expf(-alpha[lrow]));  // a * p
    }

    if (row < TOTROWS) {
#pragma unroll
      for (int ct = 0; ct < 4; ++ct) {
        float4 o;
        o.x = p[ct][0] * inv; o.y = p[ct][1] * inv;
        o.z = p[ct][2] * inv; o.w = p[ct][3] * inv;
        *(float4*)&dst[(size_t)lrow * NCLS + ct * 16 + u * 4] = o;
      }
    }
  }
}

// Gather-average 12 neighbor class rows and blend: out += (1-a)*0.5*(s0/8 + s1/4).
__launch_bounds__(256)
__global__ void blend_kernel(const float* __restrict__ cls0, const float* __restrict__ cls1,
                             const int* __restrict__ idx0, const int* __restrict__ idx1,
                             const float* __restrict__ alpha, float* __restrict__ out) {
  const int t = threadIdx.x;
  const int lane = t & 63;
  const int wv = t >> 6;
  const int g = lane >> 4;
  const int q = lane & 15;
  const int n = blockIdx.x * 16 + wv * 4 + g;

  int4 ia = *(const int4*)&idx0[n * S0];
  int4 ib = *(const int4*)&idx0[n * S0 + 4];
  int4 ic = *(const int4*)&idx1[n * S1];
  const int j0[S0] = {ia.x, ia.y, ia.z, ia.w, ib.x, ib.y, ib.z, ib.w};
  const int j1[S1] = {ic.x, ic.y, ic.z, ic.w};

  float4 s0 = make_float4(0.f, 0.f, 0.f, 0.f);
#pragma unroll
  for (int k = 0; k < S0; ++k) {
    float4 gv = *(const float4*)&cls0[(size_t)j0[k] * NCLS + q * 4];
    s0.x += gv.x; s0.y += gv.y; s0.z += gv.z; s0.w += gv.w;
  }
  float4 s1 = make_float4(0.f, 0.f, 0.f, 0.f);
#pragma unroll
  for (int k = 0; k < S1; ++k) {
    float4 gv = *(const float4*)&cls1[(size_t)j1[k] * NCLS + q * 4];
    s1.x += gv.x; s1.y += gv.y; s1.z += gv.z; s1.w += gv.w;
  }

  const float a = 1.f / (1.f + __expf(-alpha[n]));
  const float w = (1.f - a) * 0.5f;
  const float c0 = w * (1.f / S0);
  const float c1 = w * (1.f / S1);

  float* op = &out[(size_t)n * NCLS + q * 4];
  float4 o = *(const float4*)op;
  o.x += c0 * s0.x + c1 * s1.x;
  o.y += c0 * s0.y + c1 * s1.y;
  o.z += c0 * s0.z + c1 * s1.z;
  o.w += c0 * s0.w + c1 * s1.w;
  *(float4*)op = o;
}

extern "C" void kernel_launch(void* const* d_in, const int* in_sizes, int n_in,
                              void* d_out, int out_size, void* d_ws, size_t ws_size,
                              hipStream_t stream) {
  const float* h0    = (const float*)d_in[0];
  const float* tab0  = (const float*)d_in[1];
  const float* tab1  = (const float*)d_in[2];
  const int*   idx0  = (const int*)d_in[3];
  const int*   idx1  = (const int*)d_in[4];
  const float* W1    = (const float*)d_in[5];
  const float* b1    = (const float*)d_in[6];
  const float* W2    = (const float*)d_in[7];
  const float* b2    = (const float*)d_in[8];
  const float* alpha = (const float*)d_in[9];
  float* out = (float*)d_out;

  char* ws = (char*)d_ws;
  float* cls0 = (float*)ws;                                   // 10,240,000 B
  float* cls1 = (float*)(ws + 10240000);                      //  7,680,000 B
  unsigned short* w1f = (unsigned short*)(ws + 17920000);     //    131,072 B
  unsigned short* w2f = (unsigned short*)(ws + 18051072);     //     32,768 B

  prep_kernel<<<(HID * HID + HID * NCLS) / 256, 256, 0, stream>>>(W1, W2, w1f, w2f);

  const int RPB = 4 * TILES * 16;  // rows per block = 64
  mlp_all_kernel<<<(TOTROWS + RPB - 1) / RPB, 256, 0, stream>>>(
      tab0, tab1, h0, w1f, b1, w2f, b2, cls0, cls1, out, alpha);

  blend_kernel<<<N_NODE / 16, 256, 0, stream>>>(cls0, cls1, idx0, idx1, alpha, out);
}

// Round 13
// 87.559 us; speedup vs baseline: 4.2559x; 1.0514x over previous
//
#include <hip/hip_runtime.h>

#define HID 256
#define NCLS 64
#define N_NODE 65536
#define N_TAB0 40000
#define N_TAB1 30000
#define S0 8
#define S1 4
#define TILES 1                       // 16 rows/wave (R12 config: VGPR 48, 4 blocks/CU)
#define TOTROWS (N_TAB0 + N_TAB1 + N_NODE)
#define PBUF 20480                    // 20 KB buffer: 16 KB W1-pair + 4 KB W2[kt2]; x2 ping-pong = 40 KB

typedef __attribute__((ext_vector_type(8))) _Float16 f16x8;
typedef __attribute__((ext_vector_type(4))) float f32x4;

__device__ __forceinline__ unsigned short f32_to_h(float x) {
  _Float16 h = (_Float16)x;                      // v_cvt_f16_f32, RTNE
  return __builtin_bit_cast(unsigned short, h);
}
__device__ __forceinline__ unsigned pack2h(float lo, float hi) {
  return (unsigned)f32_to_h(lo) | ((unsigned)f32_to_h(hi) << 16);
}

// Pre-convert W1^T and W2^T into MFMA A-fragment order, SINGLE fp16.
// w1 frag f = nt*8+kt occupies halves [f*512,(f+1)*512): ((nt*8+kt)*64+lane)*8+j
//   -> W1[kt*32 + (lane>>4)*8 + j][nt*16 + (lane&15)]
// w2 frag f = ct*8+kt likewise -> W2[kt*32 + (lane>>4)*8 + j][ct*16 + (lane&15)]
__global__ void prep_kernel(const float* __restrict__ W1, const float* __restrict__ W2,
                            unsigned short* __restrict__ w1f, unsigned short* __restrict__ w2f) {
  int t = blockIdx.x * blockDim.x + threadIdx.x;
  if (t < HID * HID) {
    int j = t & 7, l = (t >> 3) & 63, kt = (t >> 9) & 7, nt = t >> 12;
    w1f[t] = f32_to_h(W1[(kt * 32 + (l >> 4) * 8 + j) * HID + nt * 16 + (l & 15)]);
  } else {
    int t2 = t - HID * HID;
    if (t2 < HID * NCLS) {
      int j = t2 & 7, l = (t2 >> 3) & 63, kt = (t2 >> 9) & 7, ct = t2 >> 12;
      w2f[t2] = f32_to_h(W2[(kt * 32 + (l >> 4) * 8 + j) * NCLS + ct * 16 + (l & 15)]);
    }
  }
}

// One kernel over concatenated rows [tab0 | tab1 | h0]. 4 waves/block, wave owns
// ONE 16-row tile (grid 2118, VGPR 48, ~4 blocks/CU, occ 35%). W1 staged TWO
// nt-slices per interval into a ping-pong via global_load_lds; 8 barriers.
//
// R13 CHANGE: W2[kt2] (4 KB fp16) is STAGED WITH the W1 pair instead of being
// re-read from global by every wave every interval. R12 accounting: W2 global
// re-reads were 271 MB of L2 traffic (8472 waves x 8 x 4 KB, L1 thrashed by the
// X stream) -- the single largest removable item in the serial chain whose
// sum-of-pipes (LDS 26 + L2 20 + HBM 17 + MFMA 9 us) equals the 80 us wall.
// Staged: 68 MB global_load_lds + cheap ds_reads. LDS 32->40 KB keeps 4
// blocks/CU (160/40). Occupancy/TLP exonerated (R6/R7/R12: 17->35% occ, flat).
// Spill tripwires (R5/R8/R11): VGPR <=64 is FINE here (state ~100 combined incl
// AGPR); WRITE_SIZE >> 34 MB = scratch spill = abort.
__launch_bounds__(256, 4)
__global__ void mlp_all_kernel(const float* __restrict__ tab0, const float* __restrict__ tab1,
                               const float* __restrict__ h0,
                               const unsigned short* __restrict__ w1f,
                               const float* __restrict__ b1,
                               const unsigned short* __restrict__ w2f,
                               const float* __restrict__ b2,
                               float* __restrict__ cls0, float* __restrict__ cls1,
                               float* __restrict__ out,
                               const float* __restrict__ alpha) {
  __shared__ __align__(16) char Wlds[2 * PBUF];   // 40 KB

  const int t = threadIdx.x;
  const int lane = t & 63;
  const int wv = t >> 6;
  const int nr = lane & 15;
  const int u = lane >> 4;
  const int base = (blockIdx.x * 4 + wv) * (TILES * 16);
  const int lo16 = lane * 16;

  // ---- stage W1 pair (16 frags) + W2[pair] (4 frags) = 20 x 1 KB; wave wv does q=wv*5..+4 ----
  // frag q<16: W1 frag pair*16+q at dst q*1024. frag q>=16: W2 frag (q-16)*8+pair
  // (ct=q-16, kt2=pair) at dst 16384+(q-16)*1024.
  auto STAGE = [&](int pair, int bsel) {
    char* dst = Wlds + bsel * PBUF;
#pragma unroll
    for (int i = 0; i < 5; ++i) {
      const int q = wv * 5 + i;
      const unsigned short* src = (q < 16)
          ? (w1f + (size_t)(pair * 16 + q) * 512)
          : (w2f + (size_t)((q - 16) * 8 + pair) * 512);
      __builtin_amdgcn_global_load_lds(
          (const __attribute__((address_space(1))) void*)(src + lane * 8),
          (__attribute__((address_space(3))) void*)(dst + q * 1024), 16, 0, 0);
    }
  };

  // issue the first pair before the long X-pack prologue so L2 latency hides
  STAGE(0, 0);

  // ---- X as B-fragments in registers, single fp16 ----
  f16x8 bx[TILES][8];
#pragma unroll
  for (int tl = 0; tl < TILES; ++tl) {
    const int row = base + tl * 16 + nr;
    const float* src;
    int lrow;
    if (row < N_TAB0) { src = tab0; lrow = row; }
    else if (row < N_TAB0 + N_TAB1) { src = tab1; lrow = row - N_TAB0; }
    else { src = h0; lrow = row - (N_TAB0 + N_TAB1); }
    const bool rok = (row < TOTROWS);
    const float* xrow = src + (size_t)lrow * HID;
#pragma unroll
    for (int kt = 0; kt < 8; ++kt) {
      float xv[8];
      if (rok) {
        float4 a = *(const float4*)&xrow[kt * 32 + u * 8];
        float4 b = *(const float4*)&xrow[kt * 32 + u * 8 + 4];
        xv[0] = a.x; xv[1] = a.y; xv[2] = a.z; xv[3] = a.w;
        xv[4] = b.x; xv[5] = b.y; xv[6] = b.z; xv[7] = b.w;
      } else {
#pragma unroll
        for (int j = 0; j < 8; ++j) xv[j] = 0.f;
      }
      f16x8 pk;
#pragma unroll
      for (int j = 0; j < 8; ++j) pk[j] = (_Float16)xv[j];
      bx[tl][kt] = pk;
    }
  }

  // ---- logits accumulators (bias-init) ----
  f32x4 lg[TILES][4];
#pragma unroll
  for (int ct = 0; ct < 4; ++ct) {
    float4 bv = *(const float4*)&b2[ct * 16 + u * 4];
#pragma unroll
    for (int tl = 0; tl < TILES; ++tl) {
      lg[tl][ct][0] = bv.x; lg[tl][ct][1] = bv.y;
      lg[tl][ct][2] = bv.z; lg[tl][ct][3] = bv.w;
    }
  }

  // bpermute byte-addresses: dest dword m pulls from lane nr + 16*(2*(u&1) + (m>>1))
  int addr[4];
#pragma unroll
  for (int m = 0; m < 4; ++m) addr[m] = (nr + 16 * (2 * (u & 1) + (m >> 1))) * 4;
  const bool useOdd = (u >= 2);

  // phase-1 slice: read W1 frags from pair buffer, even/odd MFMA chains.
  // slice nt lives in buffer (nt>>1)&1 at sub-offset (nt&1)*8192.
  auto slice = [&](int nt, unsigned* P0, unsigned* P1) {
    const char* wb = Wlds + ((nt >> 1) & 1) * PBUF + (nt & 1) * 8192;
    f32x4 ae[TILES], ao[TILES];
    float4 bv = *(const float4*)&b1[nt * 16 + u * 4];
#pragma unroll
    for (int tl = 0; tl < TILES; ++tl) {
      ae[tl][0] = bv.x; ae[tl][1] = bv.y; ae[tl][2] = bv.z; ae[tl][3] = bv.w;
      ao[tl][0] = 0.f;  ao[tl][1] = 0.f;  ao[tl][2] = 0.f;  ao[tl][3] = 0.f;
    }
#pragma unroll
    for (int kt = 0; kt < 8; kt += 2) {
      f16x8 ah0 = *(const f16x8*)(wb + kt * 1024 + lo16);
      f16x8 ah1 = *(const f16x8*)(wb + (kt + 1) * 1024 + lo16);
#pragma unroll
      for (int tl = 0; tl < TILES; ++tl) {
        ae[tl] = __builtin_amdgcn_mfma_f32_16x16x32_f16(ah0, bx[tl][kt], ae[tl], 0, 0, 0);
        ao[tl] = __builtin_amdgcn_mfma_f32_16x16x32_f16(ah1, bx[tl][kt + 1], ao[tl], 0, 0, 0);
      }
    }
#pragma unroll
    for (int tl = 0; tl < TILES; ++tl) {
      P0[tl] = pack2h(fmaxf(ae[tl][0] + ao[tl][0], 0.f), fmaxf(ae[tl][1] + ao[tl][1], 0.f));
      P1[tl] = pack2h(fmaxf(ae[tl][2] + ao[tl][2], 0.f), fmaxf(ae[tl][3] + ao[tl][3], 0.f));
    }
  };

  __syncthreads();   // pair 0 (incl. W2[0]) staged

  for (int kt2 = 0; kt2 < 8; ++kt2) {
    // prefetch next pair + its W2 into the other buffer (in flight all interval)
    if (kt2 + 1 < 8) STAGE(kt2 + 1, (kt2 + 1) & 1);

    unsigned E0[TILES], E1[TILES], O0[TILES], O1[TILES];
    slice(kt2 * 2, E0, E1);
    slice(kt2 * 2 + 1, O0, O1);

    // repack to phase-2 B-frags: lane (u,nr) dword m = H dims (kt2*32 + u*8 + 2m, +1)
    f16x8 bh[TILES];
#pragma unroll
    for (int tl = 0; tl < TILES; ++tl) {
      union { unsigned d[4]; f16x8 v; } r;
#pragma unroll
      for (int m = 0; m < 4; ++m) {
        int e = __builtin_amdgcn_ds_bpermute(addr[m], (int)((m & 1) ? E1[tl] : E0[tl]));
        int o = __builtin_amdgcn_ds_bpermute(addr[m], (int)((m & 1) ? O1[tl] : O0[tl]));
        r.d[m] = (unsigned)(useOdd ? o : e);
      }
      bh[tl] = r.v;
    }

    // phase 2: W2 frags from THIS buffer's staged region (LDS, not global)
    const char* w2b = Wlds + (kt2 & 1) * PBUF + 16384;
#pragma unroll
    for (int ct = 0; ct < 4; ++ct) {
      f16x8 aw = *(const f16x8*)(w2b + ct * 1024 + lo16);
#pragma unroll
      for (int tl = 0; tl < TILES; ++tl) {
        lg[tl][ct] = __builtin_amdgcn_mfma_f32_16x16x32_f16(aw, bh[tl], lg[tl][ct], 0, 0, 0);
      }
    }

    // one barrier per interval: next pair staged (syncthreads drains own vmcnt,
    // barrier makes it global) + this buffer's reads done before overwrite.
    if (kt2 + 1 < 8) __syncthreads();
  }

  // ---- softmax + segment-resolved write, per tile ----
#pragma unroll
  for (int tl = 0; tl < TILES; ++tl) {
    const int row = base + tl * 16 + nr;
    float m = lg[tl][0][0];
#pragma unroll
    for (int ct = 0; ct < 4; ++ct)
#pragma unroll
      for (int r = 0; r < 4; ++r) m = fmaxf(m, lg[tl][ct][r]);
    m = fmaxf(m, __shfl_xor(m, 16, 64));
    m = fmaxf(m, __shfl_xor(m, 32, 64));
    float p[4][4];
    float s = 0.f;
#pragma unroll
    for (int ct = 0; ct < 4; ++ct)
#pragma unroll
      for (int r = 0; r < 4; ++r) { p[ct][r] = __expf(lg[tl][ct][r] - m); s += p[ct][r]; }
    s += __shfl_xor(s, 16, 64);
    s += __shfl_xor(s, 32, 64);
    float inv = 1.f / s;

    float* dst;
    int lrow;
    if (row < N_TAB0) { dst = cls0; lrow = row; }
    else if (row < N_TAB0 + N_TAB1) { dst = cls1; lrow = row - N_TAB0; }
    else {
      dst = out; lrow = row - (N_TAB0 + N_TAB1);
      if (row < TOTROWS) inv *= 1.f / (1.f + __expf(-alpha[lrow]));  // a * p
    }

    if (row < TOTROWS) {
#pragma unroll
      for (int ct = 0; ct < 4; ++ct) {
        float4 o;
        o.x = p[ct][0] * inv; o.y = p[ct][1] * inv;
        o.z = p[ct][2] * inv; o.w = p[ct][3] * inv;
        *(float4*)&dst[(size_t)lrow * NCLS + ct * 16 + u * 4] = o;
      }
    }
  }
}

// Gather-average 12 neighbor class rows and blend: out += (1-a)*0.5*(s0/8 + s1/4).
__launch_bounds__(256)
__global__ void blend_kernel(const float* __restrict__ cls0, const float* __restrict__ cls1,
                             const int* __restrict__ idx0, const int* __restrict__ idx1,
                             const float* __restrict__ alpha, float* __restrict__ out) {
  const int t = threadIdx.x;
  const int lane = t & 63;
  const int wv = t >> 6;
  const int g = lane >> 4;
  const int q = lane & 15;
  const int n = blockIdx.x * 16 + wv * 4 + g;

  int4 ia = *(const int4*)&idx0[n * S0];
  int4 ib = *(const int4*)&idx0[n * S0 + 4];
  int4 ic = *(const int4*)&idx1[n * S1];
  const int j0[S0] = {ia.x, ia.y, ia.z, ia.w, ib.x, ib.y, ib.z, ib.w};
  const int j1[S1] = {ic.x, ic.y, ic.z, ic.w};

  float4 s0 = make_float4(0.f, 0.f, 0.f, 0.f);
#pragma unroll
  for (int k = 0; k < S0; ++k) {
    float4 gv = *(const float4*)&cls0[(size_t)j0[k] * NCLS + q * 4];
    s0.x += gv.x; s0.y += gv.y; s0.z += gv.z; s0.w += gv.w;
  }
  float4 s1 = make_float4(0.f, 0.f, 0.f, 0.f);
#pragma unroll
  for (int k = 0; k < S1; ++k) {
    float4 gv = *(const float4*)&cls1[(size_t)j1[k] * NCLS + q * 4];
    s1.x += gv.x; s1.y += gv.y; s1.z += gv.z; s1.w += gv.w;
  }

  const float a = 1.f / (1.f + __expf(-alpha[n]));
  const float w = (1.f - a) * 0.5f;
  const float c0 = w * (1.f / S0);
  const float c1 = w * (1.f / S1);

  float* op = &out[(size_t)n * NCLS + q * 4];
  float4 o = *(const float4*)op;
  o.x += c0 * s0.x + c1 * s1.x;
  o.y += c0 * s0.y + c1 * s1.y;
  o.z += c0 * s0.z + c1 * s1.z;
  o.w += c0 * s0.w + c1 * s1.w;
  *(float4*)op = o;
}

extern "C" void kernel_launch(void* const* d_in, const int* in_sizes, int n_in,
                              void* d_out, int out_size, void* d_ws, size_t ws_size,
                              hipStream_t stream) {
  const float* h0    = (const float*)d_in[0];
  const float* tab0  = (const float*)d_in[1];
  const float* tab1  = (const float*)d_in[2];
  const int*   idx0  = (const int*)d_in[3];
  const int*   idx1  = (const int*)d_in[4];
  const float* W1    = (const float*)d_in[5];
  const float* b1    = (const float*)d_in[6];
  const float* W2    = (const float*)d_in[7];
  const float* b2    = (const float*)d_in[8];
  const float* alpha = (const float*)d_in[9];
  float* out = (float*)d_out;

  char* ws = (char*)d_ws;
  float* cls0 = (float*)ws;                                   // 10,240,000 B
  float* cls1 = (float*)(ws + 10240000);                      //  7,680,000 B
  unsigned short* w1f = (unsigned short*)(ws + 17920000);     //    131,072 B
  unsigned short* w2f = (unsigned short*)(ws + 18051072);     //     32,768 B

  prep_kernel<<<(HID * HID + HID * NCLS) / 256, 256, 0, stream>>>(W1, W2, w1f, w2f);

  const int RPB = 4 * TILES * 16;  // rows per block = 64
  mlp_all_kernel<<<(TOTROWS + RPB - 1) / RPB, 256, 0, stream>>>(
      tab0, tab1, h0, w1f, b1, w2f, b2, cls0, cls1, out, alpha);

  blend_kernel<<<N_NODE / 16, 256, 0, stream>>>(cls0, cls1, idx0, idx1, alpha, out);
}

// Round 14
// 73.910 us; speedup vs baseline: 5.0418x; 1.1847x over previous
//
#include <hip/hip_runtime.h>

#define HID 256
#define NCLS 64
#define N_NODE 65536
#define N_TAB0 40000
#define N_TAB1 30000
#define S0 8
#define S1 4
#define TILES 1                       // 16 rows/wave (R12/R13 config)
#define TOTROWS (N_TAB0 + N_TAB1 + N_NODE)
#define PBUF 20480                    // 20 KB buffer: 16 KB W1-pair + 4 KB W2[kt2]; x2 ping-pong = 40 KB

typedef __attribute__((ext_vector_type(8))) _Float16 f16x8;
typedef __attribute__((ext_vector_type(4))) float f32x4;

__device__ __forceinline__ unsigned short f32_to_h(float x) {
  _Float16 h = (_Float16)x;                      // v_cvt_f16_f32, RTNE
  return __builtin_bit_cast(unsigned short, h);
}
__device__ __forceinline__ unsigned pack2h(float lo, float hi) {
  return (unsigned)f32_to_h(lo) | ((unsigned)f32_to_h(hi) << 16);
}

// Pre-convert W1^T and W2^T into MFMA A-fragment order, SINGLE fp16.
// w1 frag f = nt*8+kt occupies halves [f*512,(f+1)*512): ((nt*8+kt)*64+lane)*8+j
//   -> W1[kt*32 + (lane>>4)*8 + j][nt*16 + (lane&15)]
// w2 frag f = ct*8+kt likewise -> W2[kt*32 + (lane>>4)*8 + j][ct*16 + (lane&15)]
__global__ void prep_kernel(const float* __restrict__ W1, const float* __restrict__ W2,
                            unsigned short* __restrict__ w1f, unsigned short* __restrict__ w2f) {
  int t = blockIdx.x * blockDim.x + threadIdx.x;
  if (t < HID * HID) {
    int j = t & 7, l = (t >> 3) & 63, kt = (t >> 9) & 7, nt = t >> 12;
    w1f[t] = f32_to_h(W1[(kt * 32 + (l >> 4) * 8 + j) * HID + nt * 16 + (l & 15)]);
  } else {
    int t2 = t - HID * HID;
    if (t2 < HID * NCLS) {
      int j = t2 & 7, l = (t2 >> 3) & 63, kt = (t2 >> 9) & 7, ct = t2 >> 12;
      w2f[t2] = f32_to_h(W2[(kt * 32 + (l >> 4) * 8 + j) * NCLS + ct * 16 + (l & 15)]);
    }
  }
}

// One kernel over concatenated rows [tab0 | tab1 | h0]. 4 waves/block, wave owns
// ONE 16-row tile (grid 2118, ~4 blocks/CU, occ 35%). W1 pair + W2[kt2] staged
// per interval into a 2x20KB LDS ping-pong via global_load_lds; 8 barriers
// (R13's best schedule: 73.5 us).
//
// R14 CHANGE: cls0/cls1 intermediates stored as fp16 -- halves mlp's cls write
// traffic (27.9 -> 14 MB) and, more importantly, blend's 201 MB of L2 gather
// traffic. Probabilities in [0,1]: fp16 storage error <= 2.4e-4, attenuated by
// mean-over-12 and the (1-a)/2 weight. Blend accumulates in f32; the h0
// segment still writes f32 directly to out.
// Exonerated levers (don't retry): occupancy/TLP (occ 17->35% flat),
// barrier/vmcnt microstructure (R4 null), MFMA chain splitting (R9 negative),
// interval count <8 (R10 negative), persistent blocks (R11 spills).
// Spill tripwires (R5/R8/R11): WRITE_SIZE >> expected = scratch spill = abort.
__launch_bounds__(256, 4)
__global__ void mlp_all_kernel(const float* __restrict__ tab0, const float* __restrict__ tab1,
                               const float* __restrict__ h0,
                               const unsigned short* __restrict__ w1f,
                               const float* __restrict__ b1,
                               const unsigned short* __restrict__ w2f,
                               const float* __restrict__ b2,
                               unsigned short* __restrict__ cls0, unsigned short* __restrict__ cls1,
                               float* __restrict__ out,
                               const float* __restrict__ alpha) {
  __shared__ __align__(16) char Wlds[2 * PBUF];   // 40 KB

  const int t = threadIdx.x;
  const int lane = t & 63;
  const int wv = t >> 6;
  const int nr = lane & 15;
  const int u = lane >> 4;
  const int base = (blockIdx.x * 4 + wv) * (TILES * 16);
  const int lo16 = lane * 16;

  // ---- stage W1 pair (16 frags) + W2[pair] (4 frags) = 20 x 1 KB; wave wv does q=wv*5..+4 ----
  auto STAGE = [&](int pair, int bsel) {
    char* dst = Wlds + bsel * PBUF;
#pragma unroll
    for (int i = 0; i < 5; ++i) {
      const int q = wv * 5 + i;
      const unsigned short* src = (q < 16)
          ? (w1f + (size_t)(pair * 16 + q) * 512)
          : (w2f + (size_t)((q - 16) * 8 + pair) * 512);
      __builtin_amdgcn_global_load_lds(
          (const __attribute__((address_space(1))) void*)(src + lane * 8),
          (__attribute__((address_space(3))) void*)(dst + q * 1024), 16, 0, 0);
    }
  };

  // issue the first pair before the long X-pack prologue so L2 latency hides
  STAGE(0, 0);

  // ---- X as B-fragments in registers, single fp16 ----
  f16x8 bx[TILES][8];
#pragma unroll
  for (int tl = 0; tl < TILES; ++tl) {
    const int row = base + tl * 16 + nr;
    const float* src;
    int lrow;
    if (row < N_TAB0) { src = tab0; lrow = row; }
    else if (row < N_TAB0 + N_TAB1) { src = tab1; lrow = row - N_TAB0; }
    else { src = h0; lrow = row - (N_TAB0 + N_TAB1); }
    const bool rok = (row < TOTROWS);
    const float* xrow = src + (size_t)lrow * HID;
#pragma unroll
    for (int kt = 0; kt < 8; ++kt) {
      float xv[8];
      if (rok) {
        float4 a = *(const float4*)&xrow[kt * 32 + u * 8];
        float4 b = *(const float4*)&xrow[kt * 32 + u * 8 + 4];
        xv[0] = a.x; xv[1] = a.y; xv[2] = a.z; xv[3] = a.w;
        xv[4] = b.x; xv[5] = b.y; xv[6] = b.z; xv[7] = b.w;
      } else {
#pragma unroll
        for (int j = 0; j < 8; ++j) xv[j] = 0.f;
      }
      f16x8 pk;
#pragma unroll
      for (int j = 0; j < 8; ++j) pk[j] = (_Float16)xv[j];
      bx[tl][kt] = pk;
    }
  }

  // ---- logits accumulators (bias-init) ----
  f32x4 lg[TILES][4];
#pragma unroll
  for (int ct = 0; ct < 4; ++ct) {
    float4 bv = *(const float4*)&b2[ct * 16 + u * 4];
#pragma unroll
    for (int tl = 0; tl < TILES; ++tl) {
      lg[tl][ct][0] = bv.x; lg[tl][ct][1] = bv.y;
      lg[tl][ct][2] = bv.z; lg[tl][ct][3] = bv.w;
    }
  }

  // bpermute byte-addresses: dest dword m pulls from lane nr + 16*(2*(u&1) + (m>>1))
  int addr[4];
#pragma unroll
  for (int m = 0; m < 4; ++m) addr[m] = (nr + 16 * (2 * (u & 1) + (m >> 1))) * 4;
  const bool useOdd = (u >= 2);

  // phase-1 slice: read W1 frags from pair buffer, even/odd MFMA chains.
  // slice nt lives in buffer (nt>>1)&1 at sub-offset (nt&1)*8192.
  auto slice = [&](int nt, unsigned* P0, unsigned* P1) {
    const char* wb = Wlds + ((nt >> 1) & 1) * PBUF + (nt & 1) * 8192;
    f32x4 ae[TILES], ao[TILES];
    float4 bv = *(const float4*)&b1[nt * 16 + u * 4];
#pragma unroll
    for (int tl = 0; tl < TILES; ++tl) {
      ae[tl][0] = bv.x; ae[tl][1] = bv.y; ae[tl][2] = bv.z; ae[tl][3] = bv.w;
      ao[tl][0] = 0.f;  ao[tl][1] = 0.f;  ao[tl][2] = 0.f;  ao[tl][3] = 0.f;
    }
#pragma unroll
    for (int kt = 0; kt < 8; kt += 2) {
      f16x8 ah0 = *(const f16x8*)(wb + kt * 1024 + lo16);
      f16x8 ah1 = *(const f16x8*)(wb + (kt + 1) * 1024 + lo16);
#pragma unroll
      for (int tl = 0; tl < TILES; ++tl) {
        ae[tl] = __builtin_amdgcn_mfma_f32_16x16x32_f16(ah0, bx[tl][kt], ae[tl], 0, 0, 0);
        ao[tl] = __builtin_amdgcn_mfma_f32_16x16x32_f16(ah1, bx[tl][kt + 1], ao[tl], 0, 0, 0);
      }
    }
#pragma unroll
    for (int tl = 0; tl < TILES; ++tl) {
      P0[tl] = pack2h(fmaxf(ae[tl][0] + ao[tl][0], 0.f), fmaxf(ae[tl][1] + ao[tl][1], 0.f));
      P1[tl] = pack2h(fmaxf(ae[tl][2] + ao[tl][2], 0.f), fmaxf(ae[tl][3] + ao[tl][3], 0.f));
    }
  };

  __syncthreads();   // pair 0 (incl. W2[0]) staged

  for (int kt2 = 0; kt2 < 8; ++kt2) {
    // prefetch next pair + its W2 into the other buffer (in flight all interval)
    if (kt2 + 1 < 8) STAGE(kt2 + 1, (kt2 + 1) & 1);

    unsigned E0[TILES], E1[TILES], O0[TILES], O1[TILES];
    slice(kt2 * 2, E0, E1);
    slice(kt2 * 2 + 1, O0, O1);

    // repack to phase-2 B-frags: lane (u,nr) dword m = H dims (kt2*32 + u*8 + 2m, +1)
    f16x8 bh[TILES];
#pragma unroll
    for (int tl = 0; tl < TILES; ++tl) {
      union { unsigned d[4]; f16x8 v; } r;
#pragma unroll
      for (int m = 0; m < 4; ++m) {
        int e = __builtin_amdgcn_ds_bpermute(addr[m], (int)((m & 1) ? E1[tl] : E0[tl]));
        int o = __builtin_amdgcn_ds_bpermute(addr[m], (int)((m & 1) ? O1[tl] : O0[tl]));
        r.d[m] = (unsigned)(useOdd ? o : e);
      }
      bh[tl] = r.v;
    }

    // phase 2: W2 frags from THIS buffer's staged region (LDS, not global)
    const char* w2b = Wlds + (kt2 & 1) * PBUF + 16384;
#pragma unroll
    for (int ct = 0; ct < 4; ++ct) {
      f16x8 aw = *(const f16x8*)(w2b + ct * 1024 + lo16);
#pragma unroll
      for (int tl = 0; tl < TILES; ++tl) {
        lg[tl][ct] = __builtin_amdgcn_mfma_f32_16x16x32_f16(aw, bh[tl], lg[tl][ct], 0, 0, 0);
      }
    }

    // one barrier per interval
    if (kt2 + 1 < 8) __syncthreads();
  }

  // ---- softmax + segment-resolved write, per tile ----
#pragma unroll
  for (int tl = 0; tl < TILES; ++tl) {
    const int row = base + tl * 16 + nr;
    float m = lg[tl][0][0];
#pragma unroll
    for (int ct = 0; ct < 4; ++ct)
#pragma unroll
      for (int r = 0; r < 4; ++r) m = fmaxf(m, lg[tl][ct][r]);
    m = fmaxf(m, __shfl_xor(m, 16, 64));
    m = fmaxf(m, __shfl_xor(m, 32, 64));
    float p[4][4];
    float s = 0.f;
#pragma unroll
    for (int ct = 0; ct < 4; ++ct)
#pragma unroll
      for (int r = 0; r < 4; ++r) { p[ct][r] = __expf(lg[tl][ct][r] - m); s += p[ct][r]; }
    s += __shfl_xor(s, 16, 64);
    s += __shfl_xor(s, 32, 64);
    float inv = 1.f / s;

    if (row < TOTROWS) {
      if (row >= N_TAB0 + N_TAB1) {
        // node segment: write a * softmax directly to out (f32)
        const int lrow = row - (N_TAB0 + N_TAB1);
        const float inv2 = inv / (1.f + __expf(-alpha[lrow]));
#pragma unroll
        for (int ct = 0; ct < 4; ++ct) {
          float4 o;
          o.x = p[ct][0] * inv2; o.y = p[ct][1] * inv2;
          o.z = p[ct][2] * inv2; o.w = p[ct][3] * inv2;
          *(float4*)&out[(size_t)lrow * NCLS + ct * 16 + u * 4] = o;
        }
      } else {
        // tab segments: store softmax as fp16 (halves blend gather traffic)
        unsigned short* dsth;
        int lrow;
        if (row < N_TAB0) { dsth = cls0; lrow = row; }
        else { dsth = cls1; lrow = row - N_TAB0; }
#pragma unroll
        for (int ct = 0; ct < 4; ++ct) {
          uint2 o2;
          o2.x = pack2h(p[ct][0] * inv, p[ct][1] * inv);
          o2.y = pack2h(p[ct][2] * inv, p[ct][3] * inv);
          *(uint2*)&dsth[(size_t)lrow * NCLS + ct * 16 + u * 4] = o2;
        }
      }
    }
  }
}

// Gather-average 12 neighbor class rows (fp16) and blend:
// out += (1-a)*0.5*(s0/8 + s1/4). Accumulation in f32.
__launch_bounds__(256)
__global__ void blend_kernel(const unsigned short* __restrict__ cls0,
                             const unsigned short* __restrict__ cls1,
                             const int* __restrict__ idx0, const int* __restrict__ idx1,
                             const float* __restrict__ alpha, float* __restrict__ out) {
  const int t = threadIdx.x;
  const int lane = t & 63;
  const int wv = t >> 6;
  const int g = lane >> 4;
  const int q = lane & 15;
  const int n = blockIdx.x * 16 + wv * 4 + g;

  int4 ia = *(const int4*)&idx0[n * S0];
  int4 ib = *(const int4*)&idx0[n * S0 + 4];
  int4 ic = *(const int4*)&idx1[n * S1];
  const int j0[S0] = {ia.x, ia.y, ia.z, ia.w, ib.x, ib.y, ib.z, ib.w};
  const int j1[S1] = {ic.x, ic.y, ic.z, ic.w};

  float4 s0 = make_float4(0.f, 0.f, 0.f, 0.f);
#pragma unroll
  for (int k = 0; k < S0; ++k) {
    union { uint2 u2; _Float16 h[4]; } cv;
    cv.u2 = *(const uint2*)&cls0[(size_t)j0[k] * NCLS + q * 4];
    s0.x += (float)cv.h[0]; s0.y += (float)cv.h[1];
    s0.z += (float)cv.h[2]; s0.w += (float)cv.h[3];
  }
  float4 s1 = make_float4(0.f, 0.f, 0.f, 0.f);
#pragma unroll
  for (int k = 0; k < S1; ++k) {
    union { uint2 u2; _Float16 h[4]; } cv;
    cv.u2 = *(const uint2*)&cls1[(size_t)j1[k] * NCLS + q * 4];
    s1.x += (float)cv.h[0]; s1.y += (float)cv.h[1];
    s1.z += (float)cv.h[2]; s1.w += (float)cv.h[3];
  }

  const float a = 1.f / (1.f + __expf(-alpha[n]));
  const float w = (1.f - a) * 0.5f;
  const float c0 = w * (1.f / S0);
  const float c1 = w * (1.f / S1);

  float* op = &out[(size_t)n * NCLS + q * 4];
  float4 o = *(const float4*)op;
  o.x += c0 * s0.x + c1 * s1.x;
  o.y += c0 * s0.y + c1 * s1.y;
  o.z += c0 * s0.z + c1 * s1.z;
  o.w += c0 * s0.w + c1 * s1.w;
  *(float4*)op = o;
}

extern "C" void kernel_launch(void* const* d_in, const int* in_sizes, int n_in,
                              void* d_out, int out_size, void* d_ws, size_t ws_size,
                              hipStream_t stream) {
  const float* h0    = (const float*)d_in[0];
  const float* tab0  = (const float*)d_in[1];
  const float* tab1  = (const float*)d_in[2];
  const int*   idx0  = (const int*)d_in[3];
  const int*   idx1  = (const int*)d_in[4];
  const float* W1    = (const float*)d_in[5];
  const float* b1    = (const float*)d_in[6];
  const float* W2    = (const float*)d_in[7];
  const float* b2    = (const float*)d_in[8];
  const float* alpha = (const float*)d_in[9];
  float* out = (float*)d_out;

  char* ws = (char*)d_ws;
  unsigned short* cls0 = (unsigned short*)ws;                 //  5,120,000 B (fp16)
  unsigned short* cls1 = (unsigned short*)(ws + 5120000);     //  3,840,000 B (fp16)
  unsigned short* w1f  = (unsigned short*)(ws + 8960000);     //    131,072 B
  unsigned short* w2f  = (unsigned short*)(ws + 9091072);     //     32,768 B

  prep_kernel<<<(HID * HID + HID * NCLS) / 256, 256, 0, stream>>>(W1, W2, w1f, w2f);

  const int RPB = 4 * TILES * 16;  // rows per block = 64
  mlp_all_kernel<<<(TOTROWS + RPB - 1) / RPB, 256, 0, stream>>>(
      tab0, tab1, h0, w1f, b1, w2f, b2, cls0, cls1, out, alpha);

  blend_kernel<<<N_NODE / 16, 256, 0, stream>>>(cls0, cls1, idx0, idx1, alpha, out);
}